// Round 8
// baseline (301.964 us; speedup 1.0000x reference)
//
#include <hip/hip_runtime.h>
#include <math.h>

#define N_NODES 20000
#define N_EDGES 160000

// ws layout (bytes). ~25 MB.
static const size_t OFF_EF  = 0;                                    // ef [E][36] f32 (CSR-ordered rows)
static const size_t OFF_T   = OFF_EF  + (size_t)N_EDGES * 36 * 4;   // T [100][64][12] f32
static const size_t OFF_W1T = OFF_T   + (size_t)100 * 64 * 12 * 4;  // w1T [64][16]
static const size_t OFF_W2T = OFF_W1T + (size_t)64 * 16 * 4;        // w2T [64][64]
static const size_t OFF_W3T = OFF_W2T + (size_t)64 * 64 * 4;        // w3T [64][64]
static const size_t OFF_NOFF= OFF_W3T + (size_t)64 * 64 * 4;        // node_off [N+1] int
static const size_t OFF_NCNT= OFF_NOFF+ (size_t)(N_NODES + 1) * 4;  // cnt_i [N] int   (zeroed)
static const size_t OFF_NCUR= OFF_NCNT+ (size_t)N_NODES * 4;        // node_cur [N] int (zeroed, contiguous)
static const size_t OFF_CSR = OFF_NCUR+ (size_t)N_NODES * 4;        // csr_edges [E] int

#define PREP_W1T_END 1024
#define PREP_W2T_END (PREP_W1T_END + 4096)
#define PREP_W3T_END (PREP_W2T_END + 4096)

// mega_prep grid split: [0,25) T-build (with inline ai-table), [25,61) transposes, [61,686) histogram
#define MEGA_T_BLOCKS    25
#define MEGA_PREP_BLOCKS 36
#define MEGA_HIST_BLOCKS 625
#define MEGA_GRID (MEGA_T_BLOCKS + MEGA_PREP_BLOCKS + MEGA_HIST_BLOCKS)

__device__ __forceinline__ float silu_f(float x) {
    return x / (1.0f + __expf(-x));
}

// ---------------- K1: mega-prep — ai-table+T-build, transposes, histogram ------------
__global__ void mega_prep_kernel(const float* __restrict__ emb,
                                 const float* __restrict__ fw1, const float* __restrict__ fb1,
                                 const float* __restrict__ fw2, const float* __restrict__ fb2,
                                 const float* __restrict__ fw3, const float* __restrict__ fb3,
                                 const float* __restrict__ fc_w1, const float* __restrict__ fc_w2,
                                 const float* __restrict__ fc_w3, const float* __restrict__ fc_w4,
                                 const int* __restrict__ edst,
                                 float* __restrict__ w1t, float* __restrict__ w2t,
                                 float* __restrict__ w3t, float* __restrict__ T,
                                 int* __restrict__ cnt_i) {
    int b = blockIdx.x;
    int tid = threadIdx.x;
    if (b < MEGA_T_BLOCKS) {
        // ---- inline node-type MLP: ai[10][8] in LDS (redundant per block, trivial) ----
        __shared__ float h1s[640];   // [10][64]
        __shared__ float h2s[320];   // [10][32]
        __shared__ float ai[80];     // [10][8]
        for (int idx = tid; idx < 640; idx += 256) {
            int t = idx >> 6, j = idx & 63;
            float acc = fb1[j];
            #pragma unroll
            for (int i = 0; i < 16; i++) acc += emb[t * 16 + i] * fw1[i * 64 + j];
            h1s[idx] = silu_f(acc);
        }
        __syncthreads();
        for (int idx = tid; idx < 320; idx += 256) {
            int t = idx >> 5, j = idx & 31;
            float acc = fb2[j];
            #pragma unroll
            for (int i = 0; i < 64; i++) acc += h1s[t * 64 + i] * fw2[i * 32 + j];
            h2s[idx] = silu_f(acc);
        }
        __syncthreads();
        if (tid < 80) {
            int t = tid >> 3, j = tid & 7;
            float acc = fb3[j];
            #pragma unroll
            for (int i = 0; i < 32; i++) acc += h2s[t * 32 + i] * fw3[i * 8 + j];
            ai[tid] = acc;
        }
        __syncthreads();

        // ---- T[pair][k][12] build ----
        int idx = b * 256 + tid;
        if (idx >= 6400) return;
        int pair = idx >> 6;
        int k = idx & 63;
        int ts = pair / 10, td = pair - ts * 10;

        float a[8], bb[8];
        #pragma unroll
        for (int i = 0; i < 8; i++) a[i] = ai[ts * 8 + i];
        #pragma unroll
        for (int i = 0; i < 8; i++) bb[i] = ai[td * 8 + i];

        float sv[12];
        #pragma unroll
        for (int i = 0; i < 12; i++) sv[i] = 0.0f;

        const float* wk = fc_w4 + k * 768;
        #pragma unroll 2
        for (int u = 0; u < 8; u++) {
            #pragma unroll
            for (int v = 0; v < 8; v++) {
                float ab = a[u] * bb[v];
                const float* wp = wk + u * 32 + v * 4;
                float4 w0 = *(const float4*)(wp);
                float4 w1 = *(const float4*)(wp + 256);
                float4 w2 = *(const float4*)(wp + 512);
                sv[0] += ab * w0.x; sv[1] += ab * w0.y; sv[2]  += ab * w0.z; sv[3]  += ab * w0.w;
                sv[4] += ab * w1.x; sv[5] += ab * w1.y; sv[6]  += ab * w1.z; sv[7]  += ab * w1.w;
                sv[8] += ab * w2.x; sv[9] += ab * w2.y; sv[10] += ab * w2.z; sv[11] += ab * w2.w;
            }
        }
        float* tp = T + pair * 768 + k * 12;
        #pragma unroll
        for (int j = 0; j < 12; j++) tp[j] = sv[j];
    } else if (b < MEGA_T_BLOCKS + MEGA_PREP_BLOCKS) {
        int idx = (b - MEGA_T_BLOCKS) * 256 + tid;
        if (idx < PREP_W1T_END) {
            int j = idx >> 4, i = idx & 15;
            w1t[j * 16 + i] = fc_w1[i * 64 + j];
        } else if (idx < PREP_W2T_END) {
            int t = idx - PREP_W1T_END; int j = t >> 6, i = t & 63;
            w2t[j * 64 + i] = fc_w2[i * 64 + j];
        } else if (idx < PREP_W3T_END) {
            int t = idx - PREP_W2T_END; int j = t >> 6, i = t & 63;
            w3t[j * 64 + i] = fc_w3[i * 64 + j];
        }
    } else {
        int e = (b - MEGA_T_BLOCKS - MEGA_PREP_BLOCKS) * 256 + tid;
        if (e < N_EDGES) atomicAdd(&cnt_i[edst[e]], 1);
    }
}

// ---------------- scan: single block, exclusive prefix over 20000 counts -------------
__global__ __launch_bounds__(1024) void scan_kernel(const int* __restrict__ cnt_i,
                                                    int* __restrict__ node_off) {
    __shared__ int part[1024];
    int t = threadIdx.x;
    int base = t * 20;
    int s = 0;
    #pragma unroll 4
    for (int i = 0; i < 20; i++) {
        int n = base + i;
        if (n < N_NODES) s += cnt_i[n];
    }
    part[t] = s;
    __syncthreads();
    for (int off = 1; off < 1024; off <<= 1) {
        int v = part[t];
        int add = (t >= off) ? part[t - off] : 0;
        __syncthreads();
        part[t] = v + add;
        __syncthreads();
    }
    int run = (t == 0) ? 0 : part[t - 1];
    #pragma unroll 4
    for (int i = 0; i < 20; i++) {
        int n = base + i;
        if (n < N_NODES) { node_off[n] = run; run += cnt_i[n]; }
    }
    if (t == 1023) node_off[N_NODES] = run;
}

__global__ void scatter_kernel(const int* __restrict__ edst,
                               const int* __restrict__ node_off,
                               int* __restrict__ node_cur,
                               int* __restrict__ csr_edges) {
    int e = blockIdx.x * 256 + threadIdx.x;
    if (e >= N_EDGES) return;
    int d = edst[e];
    int slot = atomicAdd(&node_cur[d], 1);
    csr_edges[node_off[d] + slot] = e;
}

// ---------------- per-edge geometry helper ------------------------------------------
__device__ __forceinline__ void edge_geom(
        const float* __restrict__ pos, const int* __restrict__ batch,
        const int* __restrict__ esrc, const int* __restrict__ edst,
        const float* __restrict__ shifts, const float* __restrict__ cell,
        const int* __restrict__ A, int e,
        float& x, float& y, float& z, float* rb, int& pair) {
    int s = esrc[e], d = edst[e];
    int gb = batch[s];
    float t0 = shifts[e * 3 + 0], t1 = shifts[e * 3 + 1], t2 = shifts[e * 3 + 2];
    const float* C = cell + gb * 9;
    float shx = t0 * C[0] + t1 * C[3] + t2 * C[6];
    float shy = t0 * C[1] + t1 * C[4] + t2 * C[7];
    float shz = t0 * C[2] + t1 * C[5] + t2 * C[8];
    float ex = pos[d * 3 + 0] - pos[s * 3 + 0] + shx;
    float ey = pos[d * 3 + 1] - pos[s * 3 + 1] + shy;
    float ez = pos[d * 3 + 2] - pos[s * 3 + 2] + shz;
    float r = sqrtf(ex * ex + ey * ey + ez * ez);
    float inv = 1.0f / fmaxf(r, 1e-9f);
    x = ex * inv; y = ey * inv; z = ez * inv;
    const float step = 5.0f / 17.0f;
    const float istep = 17.0f / 5.0f;
    const float rsc = 4.0f / 1.12f;
    #pragma unroll
    for (int i = 0; i < 16; i++) {
        float dd = (r - (float)(i + 1) * step) * istep;
        rb[i] = __expf(-dd * dd) * rsc;
    }
    pair = A[s] * 10 + A[d];
}

// ---------------- K3: dual-edge cooperative fused kernel ----------------------------
// Block = 256 threads = 4 waves over a 128-position CSR tile; lane handles positions
// p0 = base+lane (sub 0) and p1 = p0+64 (sub 1). Wave w owns channels [16w,16w+16).
// Activations in LDS [64ch][128]; weights via wave-uniform s_loads.
__global__ __launch_bounds__(256, 4) void edge_fused_kernel(
        const float* __restrict__ pos, const int* __restrict__ batch,
        const int* __restrict__ esrc, const int* __restrict__ edst,
        const float* __restrict__ shifts, const float* __restrict__ cell,
        const int* __restrict__ A, const int* __restrict__ csr_edges,
        const float* __restrict__ w1t, const float* __restrict__ w2t,
        const float* __restrict__ w3t, const float* __restrict__ T,
        float* __restrict__ ef) {
    __shared__ float smem[8192];              // 32 KB
    int tid = threadIdx.x;
    int lane = tid & 63;
    int wq = __builtin_amdgcn_readfirstlane(tid >> 6);
    int p0 = blockIdx.x * 128 + lane;
    int p1 = p0 + 64;
    int e0 = csr_edges[p0];
    int e1 = csr_edges[p1];

    float x0, y0, z0, x1, y1, z1;
    int pair0, pair1;

    // ---- geometry + radial basis + L1 (sub 0 then sub 1; rb dies between) ----
    {
        float rb[16];
        edge_geom(pos, batch, esrc, edst, shifts, cell, A, e0, x0, y0, z0, rb, pair0);
        #pragma unroll
        for (int jj = 0; jj < 16; jj++) {
            const float* wr = w1t + (wq * 16 + jj) * 16;
            float a0 = 0, a1 = 0, a2 = 0, a3 = 0;
            #pragma unroll
            for (int i = 0; i < 16; i += 4) {
                a0 += rb[i] * wr[i];         a1 += rb[i + 1] * wr[i + 1];
                a2 += rb[i + 2] * wr[i + 2]; a3 += rb[i + 3] * wr[i + 3];
            }
            smem[(wq * 16 + jj) * 128 + lane] = silu_f(((a0 + a1) + (a2 + a3)) * 0.25f);
        }
    }
    {
        float rb[16];
        edge_geom(pos, batch, esrc, edst, shifts, cell, A, e1, x1, y1, z1, rb, pair1);
        #pragma unroll
        for (int jj = 0; jj < 16; jj++) {
            const float* wr = w1t + (wq * 16 + jj) * 16;
            float a0 = 0, a1 = 0, a2 = 0, a3 = 0;
            #pragma unroll
            for (int i = 0; i < 16; i += 4) {
                a0 += rb[i] * wr[i];         a1 += rb[i + 1] * wr[i + 1];
                a2 += rb[i + 2] * wr[i + 2]; a3 += rb[i + 3] * wr[i + 3];
            }
            smem[(wq * 16 + jj) * 128 + 64 + lane] = silu_f(((a0 + a1) + (a2 + a3)) * 0.25f);
        }
    }
    __syncthreads();

    // ---- L2: 64 -> 64, dual streams ----
    float acc0[16], acc1[16];
    #pragma unroll
    for (int jj = 0; jj < 16; jj++) { acc0[jj] = 0.0f; acc1[jj] = 0.0f; }
    #pragma unroll
    for (int c = 0; c < 4; c++) {
        float hc0[16], hc1[16];
        #pragma unroll
        for (int i = 0; i < 16; i++) {
            hc0[i] = smem[(c * 16 + i) * 128 + lane];
            hc1[i] = smem[(c * 16 + i) * 128 + 64 + lane];
        }
        #pragma unroll
        for (int jj = 0; jj < 16; jj++) {
            const float* wr = w2t + (wq * 16 + jj) * 64 + c * 16;
            #pragma unroll
            for (int i = 0; i < 16; i++) {
                acc0[jj] += hc0[i] * wr[i];
                acc1[jj] += hc1[i] * wr[i];
            }
        }
    }
    __syncthreads();                          // all L2 reads done
    #pragma unroll
    for (int jj = 0; jj < 16; jj++) {
        smem[(wq * 16 + jj) * 128 + lane]      = silu_f(acc0[jj] * 0.125f);
        smem[(wq * 16 + jj) * 128 + 64 + lane] = silu_f(acc1[jj] * 0.125f);
    }
    __syncthreads();

    // ---- L3: 64 -> 64, dual streams ----
    #pragma unroll
    for (int jj = 0; jj < 16; jj++) { acc0[jj] = 0.0f; acc1[jj] = 0.0f; }
    #pragma unroll
    for (int c = 0; c < 4; c++) {
        float hc0[16], hc1[16];
        #pragma unroll
        for (int i = 0; i < 16; i++) {
            hc0[i] = smem[(c * 16 + i) * 128 + lane];
            hc1[i] = smem[(c * 16 + i) * 128 + 64 + lane];
        }
        #pragma unroll
        for (int jj = 0; jj < 16; jj++) {
            const float* wr = w3t + (wq * 16 + jj) * 64 + c * 16;
            #pragma unroll
            for (int i = 0; i < 16; i++) {
                acc0[jj] += hc0[i] * wr[i];
                acc1[jj] += hc1[i] * wr[i];
            }
        }
    }

    // ---- T-matvec, dual streams (per-lane L2-resident gathers) ----
    const float* Tp0 = T + pair0 * 768 + wq * 16 * 12;
    const float* Tp1 = T + pair1 * 768 + wq * 16 * 12;
    float sv0[12], sv1[12];
    #pragma unroll
    for (int i = 0; i < 12; i++) { sv0[i] = 0.0f; sv1[i] = 0.0f; }
    #pragma unroll
    for (int jj = 0; jj < 16; jj++) {
        float g0 = silu_f(acc0[jj] * 0.125f);
        float g1 = silu_f(acc1[jj] * 0.125f);
        const float* tp0 = Tp0 + jj * 12;
        const float* tp1 = Tp1 + jj * 12;
        float4 a0 = *(const float4*)(tp0);
        float4 a1 = *(const float4*)(tp0 + 4);
        float4 a2 = *(const float4*)(tp0 + 8);
        float4 b0 = *(const float4*)(tp1);
        float4 b1 = *(const float4*)(tp1 + 4);
        float4 b2 = *(const float4*)(tp1 + 8);
        sv0[0] += g0 * a0.x; sv0[1] += g0 * a0.y; sv0[2]  += g0 * a0.z; sv0[3]  += g0 * a0.w;
        sv0[4] += g0 * a1.x; sv0[5] += g0 * a1.y; sv0[6]  += g0 * a1.z; sv0[7]  += g0 * a1.w;
        sv0[8] += g0 * a2.x; sv0[9] += g0 * a2.y; sv0[10] += g0 * a2.z; sv0[11] += g0 * a2.w;
        sv1[0] += g1 * b0.x; sv1[1] += g1 * b0.y; sv1[2]  += g1 * b0.z; sv1[3]  += g1 * b0.w;
        sv1[4] += g1 * b1.x; sv1[5] += g1 * b1.y; sv1[6]  += g1 * b1.z; sv1[7]  += g1 * b1.w;
        sv1[8] += g1 * b2.x; sv1[9] += g1 * b2.y; sv1[10] += g1 * b2.z; sv1[11] += g1 * b2.w;
    }
    __syncthreads();                          // all L3 reads done; reuse smem for partials

    // partials [wave][12][128] = 24 KB
    #pragma unroll
    for (int j = 0; j < 12; j++) {
        smem[(wq * 12 + j) * 128 + lane]      = sv0[j];
        smem[(wq * 12 + j) * 128 + 64 + lane] = sv1[j];
    }
    __syncthreads();

    // ---- reduction + epilogue: wave w owns output column w for both subs ----
    const float isc = 1.0f / 64.0f;
    float r00 = 0, r01 = 0, r02 = 0, r10 = 0, r11 = 0, r12 = 0;
    #pragma unroll
    for (int q = 0; q < 4; q++) {
        r00 += smem[(q * 12 + wq + 0) * 128 + lane];
        r01 += smem[(q * 12 + wq + 4) * 128 + lane];
        r02 += smem[(q * 12 + wq + 8) * 128 + lane];
        r10 += smem[(q * 12 + wq + 0) * 128 + 64 + lane];
        r11 += smem[(q * 12 + wq + 4) * 128 + 64 + lane];
        r12 += smem[(q * 12 + wq + 8) * 128 + 64 + lane];
    }
    r00 *= isc; r01 *= isc; r02 *= isc;
    r10 *= isc; r11 *= isc; r12 *= isc;

    const float S3  = 1.7320508075688772f;
    const float S15 = 3.8729833462074170f;
    const float S5  = 2.2360679774997896f;

    {
        float sh1v[3] = { S3 * y0, S3 * z0, S3 * x0 };
        float sh2v[5] = { S15 * x0 * y0, S15 * y0 * z0, 0.5f * S5 * (3.0f * z0 * z0 - 1.0f),
                          S15 * x0 * z0, 0.5f * S15 * (x0 * x0 - y0 * y0) };
        float* o = ef + (size_t)p0 * 36;
        o[wq] = r00;
        #pragma unroll
        for (int jj = 0; jj < 3; jj++) o[4 + wq * 3 + jj] = r01 * sh1v[jj];
        #pragma unroll
        for (int jj = 0; jj < 5; jj++) o[16 + wq * 5 + jj] = r02 * sh2v[jj];
    }
    {
        float sh1v[3] = { S3 * y1, S3 * z1, S3 * x1 };
        float sh2v[5] = { S15 * x1 * y1, S15 * y1 * z1, 0.5f * S5 * (3.0f * z1 * z1 - 1.0f),
                          S15 * x1 * z1, 0.5f * S15 * (x1 * x1 - y1 * y1) };
        float* o = ef + (size_t)p1 * 36;
        o[wq] = r10;
        #pragma unroll
        for (int jj = 0; jj < 3; jj++) o[4 + wq * 3 + jj] = r11 * sh1v[jj];
        #pragma unroll
        for (int jj = 0; jj < 5; jj++) o[16 + wq * 5 + jj] = r12 * sh2v[jj];
    }
}

// ---------------- K4: gather + mean (float4 stream per node) -------------------------
__global__ void gather_kernel(const float* __restrict__ ef,
                              const int* __restrict__ node_off,
                              float* __restrict__ out) {
    int idx = blockIdx.x * 256 + threadIdx.x;   // (node, float4-group)
    if (idx >= N_NODES * 9) return;
    int n = idx / 9;
    int g = idx - n * 9;
    int beg = node_off[n], end = node_off[n + 1];
    const float4* ef4 = (const float4*)ef;
    float4 s = make_float4(0.f, 0.f, 0.f, 0.f);
    for (int p = beg; p < end; p++) {
        float4 v = ef4[(size_t)p * 9 + g];      // sequential rows, coalesced
        s.x += v.x; s.y += v.y; s.z += v.z; s.w += v.w;
    }
    float c = 1.0f / fmaxf((float)(end - beg), 1.0f);
    float4 r = make_float4(s.x * c, s.y * c, s.z * c, s.w * c);
    ((float4*)out)[idx] = r;
}

extern "C" void kernel_launch(void* const* d_in, const int* in_sizes, int n_in,
                              void* d_out, int out_size, void* d_ws, size_t ws_size,
                              hipStream_t stream) {
    const float* pos    = (const float*)d_in[0];
    const int*   A      = (const int*)d_in[1];
    const int*   batch  = (const int*)d_in[2];
    const int*   esrc   = (const int*)d_in[3];
    const int*   edst   = (const int*)d_in[4];
    const float* shifts = (const float*)d_in[5];
    const float* cell   = (const float*)d_in[6];
    const float* emb    = (const float*)d_in[7];
    const float* fw1    = (const float*)d_in[8];
    const float* fb1    = (const float*)d_in[9];
    const float* fw2    = (const float*)d_in[10];
    const float* fb2    = (const float*)d_in[11];
    const float* fw3    = (const float*)d_in[12];
    const float* fb3    = (const float*)d_in[13];
    const float* fcw1   = (const float*)d_in[14];
    const float* fcw2   = (const float*)d_in[15];
    const float* fcw3   = (const float*)d_in[16];
    const float* fcw4   = (const float*)d_in[17];
    float* out = (float*)d_out;

    char* ws = (char*)d_ws;
    float* ef      = (float*)(ws + OFF_EF);
    float* T       = (float*)(ws + OFF_T);
    float* w1t     = (float*)(ws + OFF_W1T);
    float* w2t     = (float*)(ws + OFF_W2T);
    float* w3t     = (float*)(ws + OFF_W3T);
    int*   node_off= (int*)(ws + OFF_NOFF);
    int*   cnt_i   = (int*)(ws + OFF_NCNT);
    int*   node_cur= (int*)(ws + OFF_NCUR);
    int*   csr     = (int*)(ws + OFF_CSR);

    hipMemsetAsync(cnt_i, 0, (size_t)2 * N_NODES * 4, stream);

    mega_prep_kernel<<<MEGA_GRID, 256, 0, stream>>>(emb, fw1, fb1, fw2, fb2, fw3, fb3,
                                                    fcw1, fcw2, fcw3, fcw4, edst,
                                                    w1t, w2t, w3t, T, cnt_i);
    scan_kernel<<<1, 1024, 0, stream>>>(cnt_i, node_off);
    scatter_kernel<<<(N_EDGES + 255) / 256, 256, 0, stream>>>(edst, node_off, node_cur, csr);
    edge_fused_kernel<<<N_EDGES / 128, 256, 0, stream>>>(
        pos, batch, esrc, edst, shifts, cell, A, csr, w1t, w2t, w3t, T, ef);
    gather_kernel<<<(N_NODES * 9 + 255) / 256, 256, 0, stream>>>(ef, node_off, out);
}